// Round 1
// baseline (305.832 us; speedup 1.0000x reference)
//
#include <hip/hip_runtime.h>

// SimplePointPillars — bin-by-row structure (no dense staging grid):
//   1) zero_ints: clear 4096-bin histogram (16 KB)
//   2) stats_partial: per-block partial moments of q = p.W (f64)  [verified recipe]
//   3) count_kernel: histogram points into (b, y, x-half) bins
//   4) reduce_finalize: BN scale/shift A,B                        [verified recipe]
//   5) scan_kernel: 1-block exclusive scan -> bin_start / bin_cursor
//   6) reorder_kernel: scatter valid points into bin order (6.4 MB)
//   7) gather_out: per bin, accumulate into 256x64 LDS tile (+1 pad,
//      ds_add_f32), write out-slab coalesced in (C,H,W) order.
//      Zero cells come free from LDS init -> no grid zero, no transpose.
// HBM traffic: ~300 MB total (vs ~910 MB for grid+transpose pipeline).
// Classification: VERIFIED recipe (f32 chain const, *5.0f recip-mult, trunc).

#define NXG 512
#define NYXG (512 * 512)
#define CB 64
#define SBLK 256

__device__ __forceinline__ int coord_mul5(float x, float offx) {
    float t = x - offx;            // f32 subtraction
    asm volatile("" : "+v"(t));    // pin: no reassociation into the mul
    float q = t * 5.0f;            // f32 multiply by exact reciprocal (XLA lowering)
    asm volatile("" : "+v"(q));    // pin: no fold of mul+cvt
    return (int)q;                 // trunc toward zero
}

// ---------------- small zero fills ----------------
__global__ void zero_ints(int* __restrict__ p, int n) {
    int i = blockIdx.x * blockDim.x + threadIdx.x;
    if (i < n) p[i] = 0;
}

__global__ void zero_kernel(float4* __restrict__ p, long n4) {
    long i = (long)blockIdx.x * blockDim.x + threadIdx.x;
    long stride = (long)gridDim.x * blockDim.x;
    float4 z = make_float4(0.f, 0.f, 0.f, 0.f);
    for (; i < n4; i += stride) p[i] = z;
}

// ---------------- per-block partial moments of q = p.W (f64) ----------------
__global__ void stats_partial(const float4* __restrict__ pts, const float* __restrict__ W,
                              double* __restrict__ S_part, int M) {
    __shared__ float4 tile[256];
    __shared__ double sh1[256], sh2[256];
    int t = threadIdx.x;
    int lane = t & 63;
    int wv = t >> 6;
    float w0 = W[lane], w1 = W[64 + lane], w2 = W[128 + lane], w3 = W[192 + lane];
    double s1 = 0.0, s2 = 0.0;

    int chunk = (M + gridDim.x - 1) / gridDim.x;
    int base = blockIdx.x * chunk;
    int end = base + chunk; if (end > M) end = M;

    for (int i0 = base; i0 < end; i0 += 256) {
        int n = end - i0; if (n > 256) n = 256;
        __syncthreads();                       // previous tile fully consumed
        if (t < n) tile[t] = pts[i0 + t];      // coalesced 16B/lane
        __syncthreads();
        int j0 = wv * 64, j1 = j0 + 64; if (j1 > n) j1 = n;
        for (int j = j0; j < j1; ++j) {
            float4 p = tile[j];                // LDS broadcast
            float q = p.x * w0 + p.y * w1 + p.z * w2 + p.w * w3;
            double qd = (double)q;
            s1 += qd;
            s2 += qd * qd;
        }
    }
    sh1[t] = s1;
    sh2[t] = s2;
    __syncthreads();
    if (t < 64) {
        int c = t;
        S_part[(long)blockIdx.x * 128 + c] =
            (sh1[c] + sh1[64 + c]) + (sh1[128 + c] + sh1[192 + c]);
        S_part[(long)blockIdx.x * 128 + 64 + c] =
            (sh2[c] + sh2[64 + c]) + (sh2[128 + c] + sh2[192 + c]);
    }
}

// ---------------- 1-block parallel reduce of partials -> A,B ----------------
__global__ void reduce_finalize(const double* __restrict__ S_part,
                                const float* __restrict__ gamma, const float* __restrict__ beta,
                                float* __restrict__ AB, double invM) {
    __shared__ double sh[4][128];
    __shared__ double tot[128];
    int t = threadIdx.x;             // 512 threads
    int g = t >> 7, tt = t & 127;
    const double* base = S_part + (long)g * 64 * 128 + tt;   // 64 blocks per group
    double a0 = 0.0, a1 = 0.0, a2 = 0.0, a3 = 0.0;
#pragma unroll
    for (int b = 0; b < 64; b += 4) {           // 4 independent chains
        a0 += base[(long)(b + 0) * 128];
        a1 += base[(long)(b + 1) * 128];
        a2 += base[(long)(b + 2) * 128];
        a3 += base[(long)(b + 3) * 128];
    }
    sh[g][tt] = (a0 + a1) + (a2 + a3);
    __syncthreads();
    if (t < 128) tot[t] = (sh[0][t] + sh[1][t]) + (sh[2][t] + sh[3][t]);
    __syncthreads();
    if (t < 64) {
        double mu = tot[t] * invM;
        double var = tot[64 + t] * invM - mu * mu;
        double sc = (double)gamma[t] / sqrt(var + 1e-5);
        AB[t] = (float)sc;
        AB[64 + t] = (float)((double)beta[t] - mu * sc);
    }
}

// ---------------- bin histogram: bin = (b*512 + cy)*2 + (cx>>8) ----------------
__global__ void count_kernel(const float4* __restrict__ pts, int* __restrict__ counts,
                             int M, int Nper) {
    int i = blockIdx.x * blockDim.x + threadIdx.x;
    int stride = gridDim.x * blockDim.x;
    const float offx = -51.1f - 0.1f;   // f32 chain const: -51.19999694824219
    for (; i < M; i += stride) {
        float4 p = pts[i];
        int cx = coord_mul5(p.x, offx);
        int cy = coord_mul5(p.y, offx);
        if (cx < 0 || cx >= NXG || cy < 0 || cy >= NXG) continue;  // z: cz==0 always
        int b = i / Nper;
        int bin = (((b << 9) + cy) << 1) | (cx >> 8);
        atomicAdd(&counts[bin], 1);
    }
}

// ---------------- 1-block exclusive scan over NB bins ----------------
__global__ void scan_kernel(const int* __restrict__ counts, int* __restrict__ start,
                            int* __restrict__ cursor, int NB) {
    __shared__ int partial[256];
    int t = threadIdx.x;
    int chunk = (NB + 255) >> 8;
    int i0 = t * chunk;
    int i1 = i0 + chunk; if (i1 > NB) i1 = NB; if (i0 > NB) i0 = NB;
    int s = 0;
    for (int i = i0; i < i1; ++i) s += counts[i];
    partial[t] = s;
    __syncthreads();
    if (t == 0) {
        int run = 0;
        for (int k = 0; k < 256; ++k) { int v = partial[k]; partial[k] = run; run += v; }
    }
    __syncthreads();
    int run = partial[t];
    for (int i = i0; i < i1; ++i) {
        int v = counts[i];
        start[i] = run;
        cursor[i] = run;
        run += v;
    }
    if (t == 255) start[NB] = run;   // total valid points
}

// ---------------- scatter valid points into bin order ----------------
__global__ void reorder_kernel(const float4* __restrict__ pts, int* __restrict__ cursor,
                               float4* __restrict__ pts_s, int M, int Nper) {
    int i = blockIdx.x * blockDim.x + threadIdx.x;
    int stride = gridDim.x * blockDim.x;
    const float offx = -51.1f - 0.1f;
    for (; i < M; i += stride) {
        float4 p = pts[i];
        int cx = coord_mul5(p.x, offx);
        int cy = coord_mul5(p.y, offx);
        if (cx < 0 || cx >= NXG || cy < 0 || cy >= NXG) continue;
        int b = i / Nper;
        int bin = (((b << 9) + cy) << 1) | (cx >> 8);
        int idx = atomicAdd(&cursor[bin], 1);
        pts_s[idx] = p;
    }
}

// ---------------- per-bin gather: LDS tile accumulate + coalesced out write ----
// bin = b*1024 + y*2 + half; owns out[b, :, y, half*256 : half*256+256]
__global__ __launch_bounds__(256) void gather_out(
    const float4* __restrict__ pts_s, const float* __restrict__ W,
    const float* __restrict__ AB, const int* __restrict__ bin_start,
    float* __restrict__ out) {
    __shared__ float acc[256][65];   // +1 pad: (x + c) % 32 -> 2 lanes/bank, free
    int t = threadIdx.x;
    int lane = t & 63, wv = t >> 6;
    int bin = blockIdx.x;
    int half = bin & 1;
    int y = (bin >> 1) & 511;
    int b = bin >> 10;

    for (int k = t; k < 256 * 65; k += 256) ((float*)acc)[k] = 0.f;

    float w0 = W[lane], w1 = W[64 + lane], w2 = W[128 + lane], w3 = W[192 + lane];
    float A = AB[lane], Bc = AB[64 + lane];
    const float offx = -51.1f - 0.1f;
    int s = bin_start[bin], e = bin_start[bin + 1];
    __syncthreads();

    // 4 waves sweep the bin's points; software prefetch hides broadcast-load latency
    int i = s + wv;
    float4 p = make_float4(0.f, 0.f, 0.f, 0.f);
    if (i < e) p = pts_s[i];
    for (; i < e; i += 4) {
        int in = i + 4;
        float4 pn = p;
        if (in < e) pn = pts_s[in];
        int cx = coord_mul5(p.x, offx);     // identical recipe -> consistent with binning
        int x = cx - (half << 8);           // 0..255 guaranteed
        float q = p.x * w0 + p.y * w1 + p.z * w2 + p.w * w3;
        float f = fmaxf(q * A + Bc, 0.f);
        atomicAdd(&acc[x][lane], f);        // ds_add_f32, bank-conflict-free
        p = pn;
    }
    __syncthreads();

    // write slab: 64 channels x 256 x, fully coalesced (256 consecutive floats/iter)
    float* op = out + (size_t)b * CB * NYXG + (size_t)y * NXG + (half << 8) + t;
#pragma unroll 4
    for (int j = 0; j < CB; ++j) {
        op[(size_t)j * NYXG] = acc[t][j];   // LDS read bank = (t + j) % 32: free
    }
}

// ---------------- fallback: direct scatter into (B, C, H, W) ----------------
__global__ void scatter_direct(const float4* __restrict__ pts, const float* __restrict__ W,
                               const float* __restrict__ AB, float* __restrict__ out,
                               int M, int Nper) {
    int lane = threadIdx.x & 63;
    int wid = blockIdx.x * (blockDim.x >> 6) + (threadIdx.x >> 6);
    int nw = gridDim.x * (blockDim.x >> 6);
    float w0 = W[lane], w1 = W[64 + lane], w2 = W[128 + lane], w3 = W[192 + lane];
    float A = AB[lane], Bc = AB[64 + lane];
    const float offx = -51.1f - 0.1f;
    for (int i = wid; i < M; i += nw) {
        float4 p = pts[i];
        int cx = coord_mul5(p.x, offx);
        int cy = coord_mul5(p.y, offx);
        if (cx < 0 || cx >= NXG || cy < 0 || cy >= NXG) continue;
        int b = i / Nper;
        float q = p.x * w0 + p.y * w1 + p.z * w2 + p.w * w3;
        float f = fmaxf(q * A + Bc, 0.f);
        atomicAdd(&out[((long)(b * CB + lane) * NXG + cy) * NXG + cx], f);
    }
}

extern "C" void kernel_launch(void* const* d_in, const int* in_sizes, int n_in,
                              void* d_out, int out_size, void* d_ws, size_t ws_size,
                              hipStream_t stream) {
    const float4* pts = (const float4*)d_in[0];
    const float* W = (const float*)d_in[1];
    // d_in[2] = bias: cancels exactly in BN (h - mu_h), not needed.
    const float* gamma = (const float*)d_in[3];
    const float* beta = (const float*)d_in[4];
    float* out = (float*)d_out;

    int M = in_sizes[0] / 4;                    // 400000 points
    int B = out_size / (CB * NYXG);             // 4
    int Nper = M / B;                           // 100000
    int NB = B * 1024;                          // (b, y, x-half) bins

    char* wsb = (char*)d_ws;
    float* AB = (float*)(wsb + 1024);
    double* S_part = (double*)(wsb + 2048);     // 256 * 128 doubles = 256 KB

    size_t off = 2048 + (size_t)SBLK * 128 * sizeof(double);   // = 264192
    int* counts = (int*)(wsb + off);     off += (size_t)NB * 4;
    int* bin_start = (int*)(wsb + off);  off += (size_t)(NB + 1) * 4;
    int* bin_cursor = (int*)(wsb + off); off += (size_t)NB * 4;
    off = (off + 15) & ~(size_t)15;
    float4* pts_s = (float4*)(wsb + off); off += (size_t)M * 16;
    size_t need = off;                          // ~6.7 MB

    if (ws_size >= need) {
        zero_ints<<<(NB + 255) / 256, 256, 0, stream>>>(counts, NB);
        stats_partial<<<SBLK, 256, 0, stream>>>(pts, W, S_part, M);
        count_kernel<<<1024, 256, 0, stream>>>(pts, counts, M, Nper);
        reduce_finalize<<<1, 512, 0, stream>>>(S_part, gamma, beta, AB, 1.0 / (double)M);
        scan_kernel<<<1, 256, 0, stream>>>(counts, bin_start, bin_cursor, NB);
        reorder_kernel<<<1024, 256, 0, stream>>>(pts, bin_cursor, pts_s, M, Nper);
        gather_out<<<NB, 256, 0, stream>>>(pts_s, W, AB, bin_start, out);
    } else {
        zero_kernel<<<2048, 256, 0, stream>>>((float4*)out, (long)out_size / 4);
        stats_partial<<<SBLK, 256, 0, stream>>>(pts, W, S_part, M);
        reduce_finalize<<<1, 512, 0, stream>>>(S_part, gamma, beta, AB, 1.0 / (double)M);
        scatter_direct<<<2048, 256, 0, stream>>>(pts, W, AB, out, M, Nper);
    }
}

// Round 2
// 250.901 us; speedup vs baseline: 1.2189x; 1.2189x over previous
//
#include <hip/hip_runtime.h>

// SimplePointPillars — bin-by-quarter-row structure (no dense staging grid):
//   1) zero_ints: clear 8192-bin histogram (32 KB)
//   2) stats_count: per-block partial moments of q = p.W (f64) [verified
//      recipe] FUSED with bin histogram (counts from the staged tile)
//   3) reduce_finalize: BN scale/shift A,B                     [verified recipe]
//   4) scan_kernel: 1-block exclusive scan -> bin_start / bin_cursor
//   5) reorder_kernel: scatter valid points into bin order (5.8 MB)
//   6) gather_out: per bin (b, y, x-quarter): stage points -> LDS, sweep via
//      LDS broadcast, ds_add_f32 into acc[64][129] (2-way banks = free),
//      write 64x128 out-slab as float4 (dwordx4), fully coalesced (C,H,W).
//      Zero cells come free from LDS init -> no grid zero, no transpose.
//      33 KB LDS -> 4 blocks/CU (50% occupancy) vs 65 KB -> 2 (25%).
// HBM traffic: ~295 MB total. Classification: VERIFIED recipe
// (f32 chain const, *5.0f recip-mult, trunc).

#define NXG 512
#define NYXG (512 * 512)
#define CB 64
#define SBLK 256

__device__ __forceinline__ int coord_mul5(float x, float offx) {
    float t = x - offx;            // f32 subtraction
    asm volatile("" : "+v"(t));    // pin: no reassociation into the mul
    float q = t * 5.0f;            // f32 multiply by exact reciprocal (XLA lowering)
    asm volatile("" : "+v"(q));    // pin: no fold of mul+cvt
    return (int)q;                 // trunc toward zero
}

// ---------------- small zero fills ----------------
__global__ void zero_ints(int* __restrict__ p, int n) {
    int i = blockIdx.x * blockDim.x + threadIdx.x;
    if (i < n) p[i] = 0;
}

__global__ void zero_kernel(float4* __restrict__ p, long n4) {
    long i = (long)blockIdx.x * blockDim.x + threadIdx.x;
    long stride = (long)gridDim.x * blockDim.x;
    float4 z = make_float4(0.f, 0.f, 0.f, 0.f);
    for (; i < n4; i += stride) p[i] = z;
}

// ------ per-block partial moments of q = p.W (f64) + fused bin histogram ------
__global__ void stats_count(const float4* __restrict__ pts, const float* __restrict__ W,
                            double* __restrict__ S_part, int* __restrict__ counts,
                            int M, int Nper) {
    __shared__ float4 tile[256];
    __shared__ double sh1[256], sh2[256];
    int t = threadIdx.x;
    int lane = t & 63;
    int wv = t >> 6;
    float w0 = W[lane], w1 = W[64 + lane], w2 = W[128 + lane], w3 = W[192 + lane];
    const float offx = -51.1f - 0.1f;   // f32 chain const: -51.19999694824219
    double s1 = 0.0, s2 = 0.0;

    int chunk = (M + gridDim.x - 1) / gridDim.x;
    int base = blockIdx.x * chunk;
    int end = base + chunk; if (end > M) end = M;

    for (int i0 = base; i0 < end; i0 += 256) {
        int n = end - i0; if (n > 256) n = 256;
        __syncthreads();                       // previous tile fully consumed
        if (t < n) {
            float4 p = pts[i0 + t];            // coalesced 16B/lane
            tile[t] = p;
            // fused histogram: this thread's own point
            int cx = coord_mul5(p.x, offx);
            int cy = coord_mul5(p.y, offx);
            if (cx >= 0 && cx < NXG && cy >= 0 && cy < NXG) {
                int b = (i0 + t) / Nper;
                int bin = (((b << 9) + cy) << 2) | (cx >> 7);
                atomicAdd(&counts[bin], 1);
            }
        }
        __syncthreads();
        int j0 = wv * 64, j1 = j0 + 64; if (j1 > n) j1 = n;
        for (int j = j0; j < j1; ++j) {
            float4 p = tile[j];                // LDS broadcast
            float q = p.x * w0 + p.y * w1 + p.z * w2 + p.w * w3;
            double qd = (double)q;
            s1 += qd;
            s2 += qd * qd;
        }
    }
    sh1[t] = s1;
    sh2[t] = s2;
    __syncthreads();
    if (t < 64) {
        int c = t;
        S_part[(long)blockIdx.x * 128 + c] =
            (sh1[c] + sh1[64 + c]) + (sh1[128 + c] + sh1[192 + c]);
        S_part[(long)blockIdx.x * 128 + 64 + c] =
            (sh2[c] + sh2[64 + c]) + (sh2[128 + c] + sh2[192 + c]);
    }
}

// ---------------- 1-block parallel reduce of partials -> A,B ----------------
__global__ void reduce_finalize(const double* __restrict__ S_part,
                                const float* __restrict__ gamma, const float* __restrict__ beta,
                                float* __restrict__ AB, double invM) {
    __shared__ double sh[4][128];
    __shared__ double tot[128];
    int t = threadIdx.x;             // 512 threads
    int g = t >> 7, tt = t & 127;
    const double* base = S_part + (long)g * 64 * 128 + tt;   // 64 blocks per group
    double a0 = 0.0, a1 = 0.0, a2 = 0.0, a3 = 0.0;
#pragma unroll
    for (int b = 0; b < 64; b += 4) {           // 4 independent chains
        a0 += base[(long)(b + 0) * 128];
        a1 += base[(long)(b + 1) * 128];
        a2 += base[(long)(b + 2) * 128];
        a3 += base[(long)(b + 3) * 128];
    }
    sh[g][tt] = (a0 + a1) + (a2 + a3);
    __syncthreads();
    if (t < 128) tot[t] = (sh[0][t] + sh[1][t]) + (sh[2][t] + sh[3][t]);
    __syncthreads();
    if (t < 64) {
        double mu = tot[t] * invM;
        double var = tot[64 + t] * invM - mu * mu;
        double sc = (double)gamma[t] / sqrt(var + 1e-5);
        AB[t] = (float)sc;
        AB[64 + t] = (float)((double)beta[t] - mu * sc);
    }
}

// ---------------- 1-block exclusive scan over NB bins ----------------
__global__ void scan_kernel(const int* __restrict__ counts, int* __restrict__ start,
                            int* __restrict__ cursor, int NB) {
    __shared__ int partial[256];
    int t = threadIdx.x;
    int chunk = (NB + 255) >> 8;
    int i0 = t * chunk;
    int i1 = i0 + chunk; if (i1 > NB) i1 = NB; if (i0 > NB) i0 = NB;
    int s = 0;
    for (int i = i0; i < i1; ++i) s += counts[i];
    partial[t] = s;
    __syncthreads();
    if (t == 0) {
        int run = 0;
        for (int k = 0; k < 256; ++k) { int v = partial[k]; partial[k] = run; run += v; }
    }
    __syncthreads();
    int run = partial[t];
    for (int i = i0; i < i1; ++i) {
        int v = counts[i];
        start[i] = run;
        cursor[i] = run;
        run += v;
    }
    if (t == 255) start[NB] = run;   // total valid points
}

// ---------------- scatter valid points into bin order ----------------
__global__ void reorder_kernel(const float4* __restrict__ pts, int* __restrict__ cursor,
                               float4* __restrict__ pts_s, int M, int Nper) {
    int i = blockIdx.x * blockDim.x + threadIdx.x;
    int stride = gridDim.x * blockDim.x;
    const float offx = -51.1f - 0.1f;
    for (; i < M; i += stride) {
        float4 p = pts[i];
        int cx = coord_mul5(p.x, offx);
        int cy = coord_mul5(p.y, offx);
        if (cx < 0 || cx >= NXG || cy < 0 || cy >= NXG) continue;
        int b = i / Nper;
        int bin = (((b << 9) + cy) << 2) | (cx >> 7);
        int idx = atomicAdd(&cursor[bin], 1);
        pts_s[idx] = p;
    }
}

// ---------------- per-bin gather: LDS tile accumulate + float4 out write ------
// bin = b*2048 + y*4 + quarter; owns out[b, :, y, quarter*128 : quarter*128+128]
__global__ __launch_bounds__(256) void gather_out(
    const float4* __restrict__ pts_s, const float* __restrict__ W,
    const float* __restrict__ AB, const int* __restrict__ bin_start,
    float* __restrict__ out) {
    __shared__ float acc[CB][129];   // 33 KB; ds_add bank = (c + x) % 32 -> 2-way, free
    __shared__ float4 ptile[64];     // staged bin points
    int t = threadIdx.x;
    int lane = t & 63, wv = t >> 6;
    int bin = blockIdx.x;
    int quarter = bin & 3;
    int y = (bin >> 2) & 511;
    int b = bin >> 11;

    for (int k = t; k < CB * 129; k += 256) ((float*)acc)[k] = 0.f;

    float w0 = W[lane], w1 = W[64 + lane], w2 = W[128 + lane], w3 = W[192 + lane];
    float A = AB[lane], Bc = AB[64 + lane];
    const float offx = -51.1f - 0.1f;
    int s = bin_start[bin], e = bin_start[bin + 1];

    for (int i0 = s; i0 < e; i0 += 64) {
        int nn = e - i0; if (nn > 64) nn = 64;
        __syncthreads();                         // acc init / previous round done
        if (t < nn) ptile[t] = pts_s[i0 + t];    // one coalesced 16B/lane load
        __syncthreads();
        for (int j = wv; j < nn; j += 4) {
            float4 p = ptile[j];                 // LDS broadcast, ~6 cyc
            int cx = coord_mul5(p.x, offx);      // identical recipe -> consistent bin
            int x = cx - (quarter << 7);         // 0..127 guaranteed
            float q = p.x * w0 + p.y * w1 + p.z * w2 + p.w * w3;
            float f = fmaxf(q * A + Bc, 0.f);
            atomicAdd(&acc[lane][x], f);         // ds_add_f32, 2-way banks
        }
    }
    __syncthreads();

    // write 64c x 128x slab as float4: 2048 float4 / 256 threads = 8 each
    size_t obase = (size_t)b * CB * NYXG + (size_t)y * NXG + (quarter << 7);
#pragma unroll
    for (int j = 0; j < 8; ++j) {
        int idx = j * 256 + t;
        int c = idx >> 5;                        // 0..63
        int xq = (idx & 31) << 2;                // 0,4,...,124
        float4 v = make_float4(acc[c][xq], acc[c][xq + 1],
                               acc[c][xq + 2], acc[c][xq + 3]);
        *(float4*)(out + obase + (size_t)c * NYXG + xq) = v;  // dwordx4, coalesced
    }
}

// ---------------- fallback: direct scatter into (B, C, H, W) ----------------
__global__ void scatter_direct(const float4* __restrict__ pts, const float* __restrict__ W,
                               const float* __restrict__ AB, float* __restrict__ out,
                               int M, int Nper) {
    int lane = threadIdx.x & 63;
    int wid = blockIdx.x * (blockDim.x >> 6) + (threadIdx.x >> 6);
    int nw = gridDim.x * (blockDim.x >> 6);
    float w0 = W[lane], w1 = W[64 + lane], w2 = W[128 + lane], w3 = W[192 + lane];
    float A = AB[lane], Bc = AB[64 + lane];
    const float offx = -51.1f - 0.1f;
    for (int i = wid; i < M; i += nw) {
        float4 p = pts[i];
        int cx = coord_mul5(p.x, offx);
        int cy = coord_mul5(p.y, offx);
        if (cx < 0 || cx >= NXG || cy < 0 || cy >= NXG) continue;
        int b = i / Nper;
        float q = p.x * w0 + p.y * w1 + p.z * w2 + p.w * w3;
        float f = fmaxf(q * A + Bc, 0.f);
        atomicAdd(&out[((long)(b * CB + lane) * NXG + cy) * NXG + cx], f);
    }
}

extern "C" void kernel_launch(void* const* d_in, const int* in_sizes, int n_in,
                              void* d_out, int out_size, void* d_ws, size_t ws_size,
                              hipStream_t stream) {
    const float4* pts = (const float4*)d_in[0];
    const float* W = (const float*)d_in[1];
    // d_in[2] = bias: cancels exactly in BN (h - mu_h), not needed.
    const float* gamma = (const float*)d_in[3];
    const float* beta = (const float*)d_in[4];
    float* out = (float*)d_out;

    int M = in_sizes[0] / 4;                    // 400000 points
    int B = out_size / (CB * NYXG);             // 4
    int Nper = M / B;                           // 100000
    int NB = B * 2048;                          // (b, y, x-quarter) bins = 8192

    char* wsb = (char*)d_ws;
    float* AB = (float*)(wsb + 1024);
    double* S_part = (double*)(wsb + 2048);     // 256 * 128 doubles = 256 KB

    size_t off = 2048 + (size_t)SBLK * 128 * sizeof(double);   // = 264192
    int* counts = (int*)(wsb + off);     off += (size_t)NB * 4;
    int* bin_start = (int*)(wsb + off);  off += (size_t)(NB + 1) * 4;
    int* bin_cursor = (int*)(wsb + off); off += (size_t)NB * 4;
    off = (off + 15) & ~(size_t)15;
    float4* pts_s = (float4*)(wsb + off); off += (size_t)M * 16;
    size_t need = off;                          // ~6.8 MB

    if (ws_size >= need) {
        zero_ints<<<(NB + 255) / 256, 256, 0, stream>>>(counts, NB);
        stats_count<<<SBLK, 256, 0, stream>>>(pts, W, S_part, counts, M, Nper);
        reduce_finalize<<<1, 512, 0, stream>>>(S_part, gamma, beta, AB, 1.0 / (double)M);
        scan_kernel<<<1, 256, 0, stream>>>(counts, bin_start, bin_cursor, NB);
        reorder_kernel<<<1024, 256, 0, stream>>>(pts, bin_cursor, pts_s, M, Nper);
        gather_out<<<NB, 256, 0, stream>>>(pts_s, W, AB, bin_start, out);
    } else {
        zero_kernel<<<2048, 256, 0, stream>>>((float4*)out, (long)out_size / 4);
        stats_count<<<SBLK, 256, 0, stream>>>(pts, W, S_part, (int*)(wsb + 2048), M, Nper);
        reduce_finalize<<<1, 512, 0, stream>>>(S_part, gamma, beta, AB, 1.0 / (double)M);
        scatter_direct<<<2048, 256, 0, stream>>>(pts, W, AB, out, M, Nper);
    }
}